// Round 3
// baseline (1563.173 us; speedup 1.0000x reference)
//
#include <hip/hip_runtime.h>

// GATrNet forward, MI355X/gfx950.
// Precision design: logits are computed fp32-exact via f16 hi/lo splitting:
//   hn = hn_hi + hn_lo (two f16 planes), qkv GEMM runs K=1024 with duplicated
//   weight columns -> q,k fp32 acc is exact in hn; epilogue stores q,k as
//   hi/lo pairs; flash computes S = qhi*khi + qlo*khi + qhi*klo (3 MFMAs).
// LDS XOR swizzles break the 16-way bank conflicts of the naive layouts.

typedef unsigned short u16;
typedef unsigned int u32;
typedef __attribute__((ext_vector_type(4))) float f32x4;
typedef __attribute__((ext_vector_type(8))) _Float16 half8;

__device__ inline u16 f2h(float f) {
  _Float16 h = (_Float16)f;
  return __builtin_bit_cast(u16, h);
}
__device__ inline float h2f(u16 u) { return (float)__builtin_bit_cast(_Float16, u); }

// async global->LDS, 16B per lane. LDS dest = wave-uniform base + lane*16.
__device__ inline void async_cp16(const void* g, void* l) {
  __builtin_amdgcn_global_load_lds((const __attribute__((address_space(1))) u32*)g,
                                   (__attribute__((address_space(3))) u32*)l, 16, 0, 0);
}

__device__ inline f32x4 mfma16(half8 a, half8 b, f32x4 c) {
  return __builtin_amdgcn_mfma_f32_16x16x32_f16(a, b, c, 0, 0, 0);
}

// INNER_COORDS {0,2,3,4,8,9,10,14} packed 4b each
#define IC_PACK 0xEA984320u

// qkv row layout (width 5120): [q_hi 0,2048) [k_hi 2048,2304) [unused v slot]
// [q_lo 2816,4864) [k_lo 4864,5120)
#define QKV_LD 5120

// ---------------- weight prep ----------------
__global__ void build_wb_enter(const float* __restrict__ we, const float* __restrict__ blade,
                               float* __restrict__ out) {
  int idx = blockIdx.x * 256 + threadIdx.x;
  if (idx >= 32 * 48 * 16) return;
  int j = idx / 768;
  int rem = idx - j * 768;
  int ix = rem >> 4, y = rem & 15;
  int i = ix >> 4, x = ix & 15;
  float acc = 0.f;
#pragma unroll
  for (int bb = 0; bb < 9; ++bb) acc += we[j * 27 + i * 9 + bb] * blade[bb * 256 + x * 16 + y];
  out[idx] = acc;
}

// WqkvT[n][k] f16, K=1024 (k>=512 duplicates k-512 so GEMM computes (hi+lo)*w).
// n<2048 q(inner y, *log2e/16), n<2304 k(inner y), else v(full).
__global__ void build_wqkvT(const float* __restrict__ wq, const float* __restrict__ wk,
                            const float* __restrict__ wv, const float* __restrict__ blade,
                            u16* __restrict__ out) {
  int idx = blockIdx.x * 256 + threadIdx.x;
  if (idx >= 2816 * 1024) return;
  int k = idx & 1023, n = idx >> 10;
  int kk = k & 511;
  int i = kk >> 4, x = kk & 15;
  const float* w;
  int y;
  float scale = 1.0f;
  if (n < 2048) {
    int j = n >> 3;
    y = (IC_PACK >> ((n & 7) * 4)) & 15;
    w = wq + j * 288 + i * 9;
    scale = 0.09016844005556021f;  // (1/16)*log2(e)
  } else if (n < 2304) {
    int m = n - 2048;
    int j = m >> 3;
    y = (IC_PACK >> ((m & 7) * 4)) & 15;
    w = wk + j * 288 + i * 9;
  } else {
    int m = n - 2304;
    int j = m >> 4;
    y = m & 15;
    w = wv + j * 288 + i * 9;
  }
  float acc = 0.f;
#pragma unroll
  for (int bb = 0; bb < 9; ++bb) acc += w[bb] * blade[bb * 256 + x * 16 + y];
  out[idx] = f2h(acc * scale);
}

// WoutT[n][k] f16: n=(j,y)<512, k=(c,x)<4096, w_out[j][c][b]
__global__ void build_woutT(const float* __restrict__ wo, const float* __restrict__ blade,
                            u16* __restrict__ out) {
  int idx = blockIdx.x * 256 + threadIdx.x;
  if (idx >= 512 * 4096) return;
  int k = idx & 4095, n = idx >> 12;
  int j = n >> 4, y = n & 15;
  int c = k >> 4, x = k & 15;
  float acc = 0.f;
#pragma unroll
  for (int bb = 0; bb < 9; ++bb) acc += wo[j * 2304 + c * 9 + bb] * blade[bb * 256 + x * 16 + y];
  out[idx] = f2h(acc);
}

// WfinalT[n][k] f16: n=(j,y)<512, k=(i,x)<512
__global__ void build_wfinalT(const float* __restrict__ wf, const float* __restrict__ blade,
                              u16* __restrict__ out) {
  int idx = blockIdx.x * 256 + threadIdx.x;
  if (idx >= 512 * 512) return;
  int k = idx & 511, n = idx >> 9;
  int j = n >> 4, y = n & 15;
  int i = k >> 4, x = k & 15;
  float acc = 0.f;
#pragma unroll
  for (int bb = 0; bb < 9; ++bb) acc += wf[j * 288 + i * 9 + bb] * blade[bb * 256 + x * 16 + y];
  out[idx] = f2h(acc);
}

// ---------------- enter projection + equi_norm ----------------
// WG = 8 tokens x 32 channels. h fp32 (residual), hn hi/lo f16 planes (row 1024).
__global__ __launch_bounds__(256) void enter_norm(const float* __restrict__ x,
                                                  const float* __restrict__ wb,
                                                  float* __restrict__ h, u16* __restrict__ hn) {
  const int tid = threadIdx.x;
  const int tl = tid >> 5, j = tid & 31;
  const int token = blockIdx.x * 8 + tl;
  const float* xp = x + (size_t)token * 48;
  float xv[48];
#pragma unroll
  for (int q = 0; q < 12; ++q) {
    float4 t = ((const float4*)xp)[q];
    xv[q * 4 + 0] = t.x;
    xv[q * 4 + 1] = t.y;
    xv[q * 4 + 2] = t.z;
    xv[q * 4 + 3] = t.w;
  }
  float acc[16] = {};
  const float* wp = wb + j * 768;
#pragma unroll
  for (int t = 0; t < 48; ++t) {
    const float xs = xv[t];
    const float4* w4 = (const float4*)(wp + t * 16);
#pragma unroll
    for (int u = 0; u < 4; ++u) {
      float4 wv = w4[u];
      acc[u * 4 + 0] += xs * wv.x;
      acc[u * 4 + 1] += xs * wv.y;
      acc[u * 4 + 2] += xs * wv.z;
      acc[u * 4 + 3] += xs * wv.w;
    }
  }
  float ip = acc[0] * acc[0] + acc[2] * acc[2] + acc[3] * acc[3] + acc[4] * acc[4] +
             acc[8] * acc[8] + acc[9] * acc[9] + acc[10] * acc[10] + acc[14] * acc[14];
#pragma unroll
  for (int d = 1; d < 32; d <<= 1) ip += __shfl_xor(ip, d, 64);  // sum over the token's 32 lanes
  const float r = 1.0f / sqrtf(ip * (1.0f / 32.0f));
  float* hp = h + (size_t)token * 512 + j * 16;
#pragma unroll
  for (int u = 0; u < 4; ++u)
    ((float4*)hp)[u] = make_float4(acc[u * 4 + 0], acc[u * 4 + 1], acc[u * 4 + 2], acc[u * 4 + 3]);
  u16 hb[16], lb[16];
#pragma unroll
  for (int y = 0; y < 16; ++y) {
    float sv = acc[y] * r;
    u16 hv = f2h(sv);
    hb[y] = hv;
    lb[y] = f2h(sv - h2f(hv));
  }
  u16* hq = hn + (size_t)token * 1024 + j * 16;
  ((uint4*)hq)[0] = *(const uint4*)&hb[0];
  ((uint4*)hq)[1] = *(const uint4*)&hb[8];
  u16* lq = hq + 512;
  ((uint4*)lq)[0] = *(const uint4*)&lb[0];
  ((uint4*)lq)[1] = *(const uint4*)&lb[8];
}

// ---------------- 128x128 f16 MFMA GEMM, B transposed [N][K] ----------------
// LDS chunk-swizzled (p = c ^ (row&3)) to break 8-way bank conflicts.
// MODE 0: qkv  -> q/k (n<2304) hi+lo into rows of ldc, v (n>=2304) -> vT[b][vd][s]
// MODE 1: outp -> Co f16 = (acc + res)/256
// MODE 2: final-> Cf fp32 = acc*256
template <int MODE>
__global__ __launch_bounds__(256) void gemm_bt(const u16* __restrict__ A,
                                               const u16* __restrict__ BT, int M, int N, int K,
                                               u16* __restrict__ Co, float* __restrict__ Cf,
                                               const float* __restrict__ res,
                                               u16* __restrict__ vT, int ldc) {
  __shared__ u16 ltA[4096];  // [128][32], chunk-swizzled
  __shared__ u16 ltB[4096];
  const int tid = threadIdx.x;
  const int lane = tid & 63;
  const int wid = tid >> 6;
  const int quad = lane >> 4, colc = lane & 15;
  const int m0 = blockIdx.y * 128, n0 = blockIdx.x * 128;
  const int wrow = (wid >> 1) * 64, wcol = (wid & 1) * 64;
  f32x4 acc[4][4] = {};
  const int r0 = tid >> 2;
  const int swk = (((tid & 3) ^ ((tid >> 2) & 3)) << 3);  // swizzled source chunk
  const u16* Ab = A + (size_t)(m0 + r0) * K + swk;
  const u16* Ab2 = Ab + (size_t)64 * K;
  const u16* Bb = BT + (size_t)(n0 + r0) * K + swk;
  const u16* Bb2 = Bb + (size_t)64 * K;
  const int swr = ((colc & 3) << 3);  // read-side swizzle partial
  for (int k0 = 0; k0 < K; k0 += 32) {
    __syncthreads();
    async_cp16(Ab + k0, &ltA[tid * 8]);
    async_cp16(Ab2 + k0, &ltA[2048 + tid * 8]);
    async_cp16(Bb + k0, &ltB[tid * 8]);
    async_cp16(Bb2 + k0, &ltB[2048 + tid * 8]);
    __syncthreads();
    half8 af[4], bfr[4];
#pragma unroll
    for (int i2 = 0; i2 < 4; ++i2)
      af[i2] = *(const half8*)&ltA[(wrow + i2 * 16 + colc) * 32 + ((quad << 3) ^ swr)];
#pragma unroll
    for (int j2 = 0; j2 < 4; ++j2)
      bfr[j2] = *(const half8*)&ltB[(wcol + j2 * 16 + colc) * 32 + ((quad << 3) ^ swr)];
#pragma unroll
    for (int i2 = 0; i2 < 4; ++i2)
#pragma unroll
      for (int j2 = 0; j2 < 4; ++j2) acc[i2][j2] = mfma16(af[i2], bfr[j2], acc[i2][j2]);
  }
#pragma unroll
  for (int i2 = 0; i2 < 4; ++i2) {
#pragma unroll
    for (int j2 = 0; j2 < 4; ++j2) {
      const int mb = m0 + wrow + i2 * 16 + quad * 4;
      const int n = n0 + wcol + j2 * 16 + colc;
#pragma unroll
      for (int rg = 0; rg < 4; ++rg) {
        const int m = mb + rg;
        float v = acc[i2][j2][rg];
        if constexpr (MODE == 0) {
          u16 hv = f2h(v);
          if (n < 2304) {
            Co[(size_t)m * ldc + n] = hv;
            Co[(size_t)m * ldc + 2816 + n] = f2h(v - h2f(hv));
          } else {
            int b = m >> 11, s = m & 2047;
            vT[((size_t)b * 512 + (n - 2304)) * 2048 + s] = hv;
          }
        } else if constexpr (MODE == 1) {
          v += res[(size_t)m * ldc + n];
          Co[(size_t)m * ldc + n] = f2h(v * (1.0f / 256.0f));
        } else {
          Cf[(size_t)m * ldc + n] = v * 256.0f;
        }
      }
    }
  }
}

// ---------------- flash attention ----------------
// grid (qblock=32, head=8, batch=4), 256 thr. Per wave: S (3-combo split-f16)
// for its 16 q-rows, PV for its 128 v-dims over all 64 q-rows (P via LDS).
// kt/vt chunk-swizzled; k_lo read straight from global (L1-broadcast).
__global__ __launch_bounds__(256, 2) void flash_attn(const u16* __restrict__ qkv,
                                                     const u16* __restrict__ vT,
                                                     u16* __restrict__ out) {
  __shared__ u16 kt[32 * 256];   // [key][d] swizzled, 16KB
  __shared__ u16 vt[512 * 32];   // [vd][key] swizzled, 32KB
  __shared__ u16 pbuf[64 * 40];  // [qrow][key], padded to 40, 5KB
  __shared__ float alpha_s[64];
  __shared__ float l_s[64];
  const int tid = threadIdx.x, lane = tid & 63, wid = tid >> 6;
  const int quad = lane >> 4, colc = lane & 15;
  const int b = blockIdx.z, h = blockIdx.y, qb = blockIdx.x;
  const size_t boff = (size_t)b * 2048 * QKV_LD;
  half8 qh[8], ql[8];
  {
    const u16* qr = qkv + boff + (size_t)(qb * 64 + wid * 16 + colc) * QKV_LD + h * 8;
#pragma unroll
    for (int kb = 0; kb < 8; ++kb) {
      qh[kb] = *(const half8*)(qr + (kb * 4 + quad) * 64);
      ql[kb] = *(const half8*)(qr + 2816 + (kb * 4 + quad) * 64);
    }
  }
  f32x4 oacc[4][8] = {};
  float mrun[4], lrun[4];
#pragma unroll
  for (int rg = 0; rg < 4; ++rg) {
    mrun[rg] = -1e30f;
    lrun[rg] = 0.f;
  }
  const u16* kbase = qkv + boff + 2048;  // k_hi
  const u16* klA = qkv + boff + 4864 + (size_t)colc * QKV_LD + quad * 8;  // k_lo, per-lane
  const u16* vbase = vT + (size_t)b * 512 * 2048;
  const int ksw = ((colc & 7) << 3);  // kt read swizzle partial
  const int vsw = ((colc & 3) << 3);  // vt read swizzle partial
  for (int t0 = 0; t0 < 2048; t0 += 32) {
    __syncthreads();
#pragma unroll
    for (int rr = 0; rr < 4; ++rr) {
      int e = rr * 256 + tid;
      int key = e >> 5, c = e & 31;
      async_cp16(kbase + (size_t)(t0 + key) * QKV_LD + ((c ^ (key & 7)) << 3), &kt[e * 8]);
    }
#pragma unroll
    for (int rr = 0; rr < 8; ++rr) {
      int e = rr * 256 + tid;
      int vd = e >> 2, c = e & 3;
      async_cp16(vbase + (size_t)vd * 2048 + t0 + ((c ^ (vd & 3)) << 3), &vt[e * 8]);
    }
    __syncthreads();
    // S [16q x 32k], fp32-exact: qhi*khi + qlo*khi + qhi*klo
    f32x4 sfr[2] = {};
    const u16* kl0 = klA + (size_t)t0 * QKV_LD;
    const u16* kl1 = kl0 + (size_t)16 * QKV_LD;
#pragma unroll
    for (int kb = 0; kb < 8; ++kb) {
      half8 khi0 = *(const half8*)&kt[(0 * 16 + colc) * 256 + ((((kb * 4 + quad) << 3)) ^ ksw)];
      half8 khi1 = *(const half8*)&kt[(1 * 16 + colc) * 256 + ((((kb * 4 + quad) << 3)) ^ ksw)];
      half8 klo0 = *(const half8*)(kl0 + kb * 32);
      half8 klo1 = *(const half8*)(kl1 + kb * 32);
      sfr[0] = mfma16(qh[kb], khi0, sfr[0]);
      sfr[0] = mfma16(ql[kb], khi0, sfr[0]);
      sfr[0] = mfma16(qh[kb], klo0, sfr[0]);
      sfr[1] = mfma16(qh[kb], khi1, sfr[1]);
      sfr[1] = mfma16(ql[kb], khi1, sfr[1]);
      sfr[1] = mfma16(qh[kb], klo1, sfr[1]);
    }
    // online softmax (exp2 domain)
    float mx[4];
#pragma unroll
    for (int rg = 0; rg < 4; ++rg) mx[rg] = fmaxf(sfr[0][rg], sfr[1][rg]);
#pragma unroll
    for (int d = 1; d < 16; d <<= 1)
#pragma unroll
      for (int rg = 0; rg < 4; ++rg) mx[rg] = fmaxf(mx[rg], __shfl_xor(mx[rg], d, 64));
    float al[4], pv0[4], pv1[4], rs[4];
#pragma unroll
    for (int rg = 0; rg < 4; ++rg) {
      float mn = fmaxf(mrun[rg], mx[rg]);
      al[rg] = exp2f(mrun[rg] - mn);
      mrun[rg] = mn;
      pv0[rg] = exp2f(sfr[0][rg] - mn);
      pv1[rg] = exp2f(sfr[1][rg] - mn);
      rs[rg] = pv0[rg] + pv1[rg];
    }
#pragma unroll
    for (int d = 1; d < 16; d <<= 1)
#pragma unroll
      for (int rg = 0; rg < 4; ++rg) rs[rg] += __shfl_xor(rs[rg], d, 64);
    const int prow = wid * 16 + quad * 4;
#pragma unroll
    for (int rg = 0; rg < 4; ++rg) {
      lrun[rg] = lrun[rg] * al[rg] + rs[rg];
      pbuf[(prow + rg) * 40 + colc] = f2h(pv0[rg]);
      pbuf[(prow + rg) * 40 + 16 + colc] = f2h(pv1[rg]);
    }
    if (colc == 0) {
#pragma unroll
      for (int rg = 0; rg < 4; ++rg) alpha_s[prow + rg] = al[rg];
    }
    __syncthreads();
    // PV: this wave's 128 v-dims, all 64 q-rows
    half8 pf[4];
#pragma unroll
    for (int pa = 0; pa < 4; ++pa) pf[pa] = *(const half8*)&pbuf[(pa * 16 + colc) * 40 + quad * 8];
    float av[4][4];
#pragma unroll
    for (int pa = 0; pa < 4; ++pa)
#pragma unroll
      for (int rg = 0; rg < 4; ++rg) av[pa][rg] = alpha_s[pa * 16 + quad * 4 + rg];
#pragma unroll
    for (int pa = 0; pa < 4; ++pa)
#pragma unroll
      for (int vb = 0; vb < 8; ++vb)
#pragma unroll
        for (int rg = 0; rg < 4; ++rg) oacc[pa][vb][rg] *= av[pa][rg];
#pragma unroll
    for (int vb = 0; vb < 8; ++vb) {
      half8 vf = *(const half8*)&vt[(wid * 128 + vb * 16 + colc) * 32 + ((quad << 3) ^ vsw)];
#pragma unroll
      for (int pa = 0; pa < 4; ++pa) oacc[pa][vb] = mfma16(pf[pa], vf, oacc[pa][vb]);
    }
  }
  {
    const int prow = wid * 16 + quad * 4;
    if (colc == 0) {
#pragma unroll
      for (int rg = 0; rg < 4; ++rg) l_s[prow + rg] = lrun[rg];
    }
  }
  __syncthreads();
  u16* ob = out + ((size_t)b * 2048 + qb * 64) * 4096 + h * 512 + wid * 128;
#pragma unroll
  for (int pa = 0; pa < 4; ++pa) {
    float li[4];
#pragma unroll
    for (int rg = 0; rg < 4; ++rg) li[rg] = 1.0f / l_s[pa * 16 + quad * 4 + rg];
#pragma unroll
    for (int vb = 0; vb < 8; ++vb)
#pragma unroll
      for (int rg = 0; rg < 4; ++rg)
        ob[(size_t)(pa * 16 + quad * 4 + rg) * 4096 + vb * 16 + colc] =
            f2h(oacc[pa][vb][rg] * li[rg]);
  }
}

// ---------------- launcher ----------------
extern "C" void kernel_launch(void* const* d_in, const int* in_sizes, int n_in, void* d_out,
                              int out_size, void* d_ws, size_t ws_size, hipStream_t stream) {
  const float* x = (const float*)d_in[0];
  const float* blade = (const float*)d_in[1];
  const float* w_enter = (const float*)d_in[2];
  const float* w_q = (const float*)d_in[3];
  const float* w_k = (const float*)d_in[4];
  const float* w_v = (const float*)d_in[5];
  const float* w_out = (const float*)d_in[6];
  const float* w_final = (const float*)d_in[7];
  float* out = (float*)d_out;

  char* ws = (char*)d_ws;
  size_t off = 0;
  auto alloc = [&](size_t bytes) {
    void* p = ws + off;
    off = (off + bytes + 255) & ~(size_t)255;
    return p;
  };
  float* wb_enter = (float*)alloc((size_t)32 * 48 * 16 * 4);
  u16* wqkvT = (u16*)alloc((size_t)2816 * 1024 * 2);
  u16* woutT = (u16*)alloc((size_t)512 * 4096 * 2);
  u16* wfinT = (u16*)alloc((size_t)512 * 512 * 2);
  float* hbuf = (float*)alloc((size_t)8192 * 512 * 4);
  u16* hn2 = (u16*)alloc((size_t)8192 * 1024 * 2);
  u16* qkv2 = (u16*)alloc((size_t)8192 * QKV_LD * 2);
  u16* vTb = (u16*)alloc((size_t)4 * 512 * 2048 * 2);
  u16* attno = (u16*)alloc((size_t)8192 * 4096 * 2);
  u16* h2 = (u16*)alloc((size_t)8192 * 512 * 2);

  build_wb_enter<<<96, 256, 0, stream>>>(w_enter, blade, wb_enter);
  build_wqkvT<<<11264, 256, 0, stream>>>(w_q, w_k, w_v, blade, wqkvT);
  build_woutT<<<8192, 256, 0, stream>>>(w_out, blade, woutT);
  build_wfinalT<<<1024, 256, 0, stream>>>(w_final, blade, wfinT);
  enter_norm<<<1024, 256, 0, stream>>>(x, wb_enter, hbuf, hn2);
  gemm_bt<0><<<dim3(22, 64), 256, 0, stream>>>(hn2, wqkvT, 8192, 2816, 1024, qkv2, nullptr,
                                               nullptr, vTb, QKV_LD);
  flash_attn<<<dim3(32, 8, 4), 256, 0, stream>>>(qkv2, vTb, attno);
  gemm_bt<1><<<dim3(4, 64), 256, 0, stream>>>(attno, woutT, 8192, 512, 4096, h2, nullptr, hbuf,
                                              nullptr, 512);
  gemm_bt<2><<<dim3(4, 64), 256, 0, stream>>>(h2, wfinT, 8192, 512, 512, nullptr, out, nullptr,
                                              nullptr, 512);
}

// Round 4
// 1553.336 us; speedup vs baseline: 1.0063x; 1.0063x over previous
//
#include <hip/hip_runtime.h>

// GATrNet forward, MI355X/gfx950.
// Precision design: logits are computed fp32-exact via f16 hi/lo splitting:
//   hn = hn_hi + hn_lo (two f16 planes), qkv GEMM runs K=1024 with duplicated
//   weight columns; epilogue stores q,k as hi/lo pairs; flash computes
//   S = qhi*khi + qlo*khi + qhi*klo (3 MFMA combos).
// Flash structure (r4): ONE barrier per K-tile. kt (K_hi) double-buffered in
// LDS, prefetch issued at loop top and drained by the same barrier that
// publishes pbuf; V and k_lo are plain VGPR global loads (L1-broadcast),
// which pipeline freely across barriers.

typedef unsigned short u16;
typedef unsigned int u32;
typedef __attribute__((ext_vector_type(4))) float f32x4;
typedef __attribute__((ext_vector_type(8))) _Float16 half8;

__device__ inline u16 f2h(float f) {
  _Float16 h = (_Float16)f;
  return __builtin_bit_cast(u16, h);
}
__device__ inline float h2f(u16 u) { return (float)__builtin_bit_cast(_Float16, u); }

// async global->LDS, 16B per lane. LDS dest = wave-uniform base + lane*16.
__device__ inline void async_cp16(const void* g, void* l) {
  __builtin_amdgcn_global_load_lds((const __attribute__((address_space(1))) u32*)g,
                                   (__attribute__((address_space(3))) u32*)l, 16, 0, 0);
}

__device__ inline f32x4 mfma16(half8 a, half8 b, f32x4 c) {
  return __builtin_amdgcn_mfma_f32_16x16x32_f16(a, b, c, 0, 0, 0);
}

// INNER_COORDS {0,2,3,4,8,9,10,14} packed 4b each
#define IC_PACK 0xEA984320u

// qkv row layout (width 5120): [q_hi 0,2048) [k_hi 2048,2304) [unused v slot]
// [q_lo 2816,4864) [k_lo 4864,5120)
#define QKV_LD 5120

// ---------------- weight prep ----------------
__global__ void build_wb_enter(const float* __restrict__ we, const float* __restrict__ blade,
                               float* __restrict__ out) {
  int idx = blockIdx.x * 256 + threadIdx.x;
  if (idx >= 32 * 48 * 16) return;
  int j = idx / 768;
  int rem = idx - j * 768;
  int ix = rem >> 4, y = rem & 15;
  int i = ix >> 4, x = ix & 15;
  float acc = 0.f;
#pragma unroll
  for (int bb = 0; bb < 9; ++bb) acc += we[j * 27 + i * 9 + bb] * blade[bb * 256 + x * 16 + y];
  out[idx] = acc;
}

// WqkvT[n][k] f16, K=1024 (k>=512 duplicates k-512 so GEMM computes (hi+lo)*w).
// n<2048 q(inner y, *log2e/16), n<2304 k(inner y), else v(full).
__global__ void build_wqkvT(const float* __restrict__ wq, const float* __restrict__ wk,
                            const float* __restrict__ wv, const float* __restrict__ blade,
                            u16* __restrict__ out) {
  int idx = blockIdx.x * 256 + threadIdx.x;
  if (idx >= 2816 * 1024) return;
  int k = idx & 1023, n = idx >> 10;
  int kk = k & 511;
  int i = kk >> 4, x = kk & 15;
  const float* w;
  int y;
  float scale = 1.0f;
  if (n < 2048) {
    int j = n >> 3;
    y = (IC_PACK >> ((n & 7) * 4)) & 15;
    w = wq + j * 288 + i * 9;
    scale = 0.09016844005556021f;  // (1/16)*log2(e)
  } else if (n < 2304) {
    int m = n - 2048;
    int j = m >> 3;
    y = (IC_PACK >> ((m & 7) * 4)) & 15;
    w = wk + j * 288 + i * 9;
  } else {
    int m = n - 2304;
    int j = m >> 4;
    y = m & 15;
    w = wv + j * 288 + i * 9;
  }
  float acc = 0.f;
#pragma unroll
  for (int bb = 0; bb < 9; ++bb) acc += w[bb] * blade[bb * 256 + x * 16 + y];
  out[idx] = f2h(acc * scale);
}

// WoutT[n][k] f16: n=(j,y)<512, k=(c,x)<4096, w_out[j][c][b]
__global__ void build_woutT(const float* __restrict__ wo, const float* __restrict__ blade,
                            u16* __restrict__ out) {
  int idx = blockIdx.x * 256 + threadIdx.x;
  if (idx >= 512 * 4096) return;
  int k = idx & 4095, n = idx >> 12;
  int j = n >> 4, y = n & 15;
  int c = k >> 4, x = k & 15;
  float acc = 0.f;
#pragma unroll
  for (int bb = 0; bb < 9; ++bb) acc += wo[j * 2304 + c * 9 + bb] * blade[bb * 256 + x * 16 + y];
  out[idx] = f2h(acc);
}

// WfinalT[n][k] f16: n=(j,y)<512, k=(i,x)<512
__global__ void build_wfinalT(const float* __restrict__ wf, const float* __restrict__ blade,
                              u16* __restrict__ out) {
  int idx = blockIdx.x * 256 + threadIdx.x;
  if (idx >= 512 * 512) return;
  int k = idx & 511, n = idx >> 9;
  int j = n >> 4, y = n & 15;
  int i = k >> 4, x = k & 15;
  float acc = 0.f;
#pragma unroll
  for (int bb = 0; bb < 9; ++bb) acc += wf[j * 288 + i * 9 + bb] * blade[bb * 256 + x * 16 + y];
  out[idx] = f2h(acc);
}

// ---------------- enter projection + equi_norm ----------------
// WG = 8 tokens x 32 channels. h fp32 (residual), hn hi/lo f16 planes (row 1024).
__global__ __launch_bounds__(256) void enter_norm(const float* __restrict__ x,
                                                  const float* __restrict__ wb,
                                                  float* __restrict__ h, u16* __restrict__ hn) {
  const int tid = threadIdx.x;
  const int tl = tid >> 5, j = tid & 31;
  const int token = blockIdx.x * 8 + tl;
  const float* xp = x + (size_t)token * 48;
  float xv[48];
#pragma unroll
  for (int q = 0; q < 12; ++q) {
    float4 t = ((const float4*)xp)[q];
    xv[q * 4 + 0] = t.x;
    xv[q * 4 + 1] = t.y;
    xv[q * 4 + 2] = t.z;
    xv[q * 4 + 3] = t.w;
  }
  float acc[16] = {};
  const float* wp = wb + j * 768;
#pragma unroll
  for (int t = 0; t < 48; ++t) {
    const float xs = xv[t];
    const float4* w4 = (const float4*)(wp + t * 16);
#pragma unroll
    for (int u = 0; u < 4; ++u) {
      float4 wv = w4[u];
      acc[u * 4 + 0] += xs * wv.x;
      acc[u * 4 + 1] += xs * wv.y;
      acc[u * 4 + 2] += xs * wv.z;
      acc[u * 4 + 3] += xs * wv.w;
    }
  }
  float ip = acc[0] * acc[0] + acc[2] * acc[2] + acc[3] * acc[3] + acc[4] * acc[4] +
             acc[8] * acc[8] + acc[9] * acc[9] + acc[10] * acc[10] + acc[14] * acc[14];
#pragma unroll
  for (int d = 1; d < 32; d <<= 1) ip += __shfl_xor(ip, d, 64);  // sum over the token's 32 lanes
  const float r = 1.0f / sqrtf(ip * (1.0f / 32.0f));
  float* hp = h + (size_t)token * 512 + j * 16;
#pragma unroll
  for (int u = 0; u < 4; ++u)
    ((float4*)hp)[u] = make_float4(acc[u * 4 + 0], acc[u * 4 + 1], acc[u * 4 + 2], acc[u * 4 + 3]);
  u16 hb[16], lb[16];
#pragma unroll
  for (int y = 0; y < 16; ++y) {
    float sv = acc[y] * r;
    u16 hv = f2h(sv);
    hb[y] = hv;
    lb[y] = f2h(sv - h2f(hv));
  }
  u16* hq = hn + (size_t)token * 1024 + j * 16;
  ((uint4*)hq)[0] = *(const uint4*)&hb[0];
  ((uint4*)hq)[1] = *(const uint4*)&hb[8];
  u16* lq = hq + 512;
  ((uint4*)lq)[0] = *(const uint4*)&lb[0];
  ((uint4*)lq)[1] = *(const uint4*)&lb[8];
}

// ---------------- 128x128 f16 MFMA GEMM, B transposed [N][K] ----------------
// LDS chunk-swizzled (p = c ^ (row&3)) to break 8-way bank conflicts.
// MODE 0: qkv  -> q/k (n<2304) hi+lo into rows of ldc, v (n>=2304) -> vT[b][vd][s]
// MODE 1: outp -> Co f16 = (acc + res)/256
// MODE 2: final-> Cf fp32 = acc*256
template <int MODE>
__global__ __launch_bounds__(256) void gemm_bt(const u16* __restrict__ A,
                                               const u16* __restrict__ BT, int M, int N, int K,
                                               u16* __restrict__ Co, float* __restrict__ Cf,
                                               const float* __restrict__ res,
                                               u16* __restrict__ vT, int ldc) {
  __shared__ u16 ltA[4096];  // [128][32], chunk-swizzled
  __shared__ u16 ltB[4096];
  const int tid = threadIdx.x;
  const int lane = tid & 63;
  const int wid = tid >> 6;
  const int quad = lane >> 4, colc = lane & 15;
  const int m0 = blockIdx.y * 128, n0 = blockIdx.x * 128;
  const int wrow = (wid >> 1) * 64, wcol = (wid & 1) * 64;
  f32x4 acc[4][4] = {};
  const int r0 = tid >> 2;
  const int swk = (((tid & 3) ^ ((tid >> 2) & 3)) << 3);  // swizzled source chunk
  const u16* Ab = A + (size_t)(m0 + r0) * K + swk;
  const u16* Ab2 = Ab + (size_t)64 * K;
  const u16* Bb = BT + (size_t)(n0 + r0) * K + swk;
  const u16* Bb2 = Bb + (size_t)64 * K;
  const int swr = ((colc & 3) << 3);  // read-side swizzle partial
  for (int k0 = 0; k0 < K; k0 += 32) {
    __syncthreads();
    async_cp16(Ab + k0, &ltA[tid * 8]);
    async_cp16(Ab2 + k0, &ltA[2048 + tid * 8]);
    async_cp16(Bb + k0, &ltB[tid * 8]);
    async_cp16(Bb2 + k0, &ltB[2048 + tid * 8]);
    __syncthreads();
    half8 af[4], bfr[4];
#pragma unroll
    for (int i2 = 0; i2 < 4; ++i2)
      af[i2] = *(const half8*)&ltA[(wrow + i2 * 16 + colc) * 32 + ((quad << 3) ^ swr)];
#pragma unroll
    for (int j2 = 0; j2 < 4; ++j2)
      bfr[j2] = *(const half8*)&ltB[(wcol + j2 * 16 + colc) * 32 + ((quad << 3) ^ swr)];
#pragma unroll
    for (int i2 = 0; i2 < 4; ++i2)
#pragma unroll
      for (int j2 = 0; j2 < 4; ++j2) acc[i2][j2] = mfma16(af[i2], bfr[j2], acc[i2][j2]);
  }
#pragma unroll
  for (int i2 = 0; i2 < 4; ++i2) {
#pragma unroll
    for (int j2 = 0; j2 < 4; ++j2) {
      const int mb = m0 + wrow + i2 * 16 + quad * 4;
      const int n = n0 + wcol + j2 * 16 + colc;
#pragma unroll
      for (int rg = 0; rg < 4; ++rg) {
        const int m = mb + rg;
        float v = acc[i2][j2][rg];
        if constexpr (MODE == 0) {
          u16 hv = f2h(v);
          if (n < 2304) {
            Co[(size_t)m * ldc + n] = hv;
            Co[(size_t)m * ldc + 2816 + n] = f2h(v - h2f(hv));
          } else {
            int b = m >> 11, s = m & 2047;
            vT[((size_t)b * 512 + (n - 2304)) * 2048 + s] = hv;
          }
        } else if constexpr (MODE == 1) {
          v += res[(size_t)m * ldc + n];
          Co[(size_t)m * ldc + n] = f2h(v * (1.0f / 256.0f));
        } else {
          Cf[(size_t)m * ldc + n] = v * 256.0f;
        }
      }
    }
  }
}

// ---------------- flash attention ----------------
// grid (qblock=32, head=8, batch=4), 256 thr. Per wave: S (3-combo split-f16)
// for its 16 q-rows, PV for its 128 v-dims over all 64 q-rows (P via LDS).
// ONE barrier per tile: kt double-buffered (prefetch issued at loop top,
// drained by the pbuf-publishing barrier); V and k_lo are VGPR global loads.
__global__ __launch_bounds__(256, 2) void flash_attn(const u16* __restrict__ qkv,
                                                     const u16* __restrict__ vT,
                                                     u16* __restrict__ out) {
  __shared__ u16 kt[2 * 32 * 256];   // [buf][key][d] swizzled, 2x16KB
  __shared__ u16 pbuf[2 * 64 * 40];  // [buf][qrow][key], padded to 40
  __shared__ float alpha_s[2 * 64];
  __shared__ float l_s[64];
  const int tid = threadIdx.x, lane = tid & 63, wid = tid >> 6;
  const int quad = lane >> 4, colc = lane & 15;
  const int b = blockIdx.z, h = blockIdx.y, qb = blockIdx.x;
  const size_t boff = (size_t)b * 2048 * QKV_LD;
  half8 qh[8], ql[8];
  {
    const u16* qr = qkv + boff + (size_t)(qb * 64 + wid * 16 + colc) * QKV_LD + h * 8;
#pragma unroll
    for (int kb = 0; kb < 8; ++kb) {
      qh[kb] = *(const half8*)(qr + (kb * 4 + quad) * 64);
      ql[kb] = *(const half8*)(qr + 2816 + (kb * 4 + quad) * 64);
    }
  }
  f32x4 oacc[4][8] = {};
  float mrun[4], lrun[4];
#pragma unroll
  for (int rg = 0; rg < 4; ++rg) {
    mrun[rg] = -1e30f;
    lrun[rg] = 0.f;
  }
  const u16* kbase = qkv + boff + 2048;  // k_hi
  const u16* klA = qkv + boff + 4864 + (size_t)colc * QKV_LD + quad * 8;  // k_lo per-lane
  const u16* vbase = vT + (size_t)b * 512 * 2048;
  const u16* vrow = vbase + (size_t)(wid * 128 + colc) * 2048 + quad * 8;  // per-lane V row
  const int ksw = ((colc & 7) << 3);  // kt read swizzle partial
  // staging lane roles (4 cp16 per thread per tile)
  const int skey0 = tid >> 5, sc0 = tid & 31;  // +rr*8 keys
  // prologue: stage kt buf0 for t0=0
#pragma unroll
  for (int rr = 0; rr < 4; ++rr) {
    int key = skey0 + rr * 8;
    async_cp16(kbase + (size_t)key * QKV_LD + ((sc0 ^ (key & 7)) << 3),
               &kt[(skey0 * 32 + sc0 + rr * 256) * 8]);
  }
  __syncthreads();
  for (int it = 0; it < 64; ++it) {
    const int t0 = it * 32;
    const int buf = it & 1;
    const int nbuf = buf ^ 1;
    // issue next tile's kt prefetch (drained by this tile's barrier)
    {
      const int tn = (it == 63) ? t0 : t0 + 32;
#pragma unroll
      for (int rr = 0; rr < 4; ++rr) {
        int key = skey0 + rr * 8;
        async_cp16(kbase + (size_t)(tn + key) * QKV_LD + ((sc0 ^ (key & 7)) << 3),
                   &kt[nbuf * 8192 + (skey0 * 32 + sc0 + rr * 256) * 8]);
      }
    }
    // S [16q x 32k], fp32-exact: qhi*khi + qlo*khi first (LDS-fed), then qhi*klo
    f32x4 sfr[2] = {};
    const u16* kl0 = klA + (size_t)t0 * QKV_LD;
    const u16* kl1 = kl0 + (size_t)16 * QKV_LD;
    const u16* ktb = &kt[buf * 8192];
#pragma unroll
    for (int kb = 0; kb < 8; ++kb) {
      half8 khi0 = *(const half8*)&ktb[(0 * 16 + colc) * 256 + (((kb * 4 + quad) << 3) ^ ksw)];
      half8 khi1 = *(const half8*)&ktb[(1 * 16 + colc) * 256 + (((kb * 4 + quad) << 3) ^ ksw)];
      sfr[0] = mfma16(qh[kb], khi0, sfr[0]);
      sfr[0] = mfma16(ql[kb], khi0, sfr[0]);
      sfr[1] = mfma16(qh[kb], khi1, sfr[1]);
      sfr[1] = mfma16(ql[kb], khi1, sfr[1]);
    }
#pragma unroll
    for (int kb = 0; kb < 8; ++kb) {
      half8 klo0 = *(const half8*)(kl0 + kb * 32);
      half8 klo1 = *(const half8*)(kl1 + kb * 32);
      sfr[0] = mfma16(qh[kb], klo0, sfr[0]);
      sfr[1] = mfma16(qh[kb], klo1, sfr[1]);
    }
    // online softmax (exp2 domain)
    float mx[4];
#pragma unroll
    for (int rg = 0; rg < 4; ++rg) mx[rg] = fmaxf(sfr[0][rg], sfr[1][rg]);
#pragma unroll
    for (int d = 1; d < 16; d <<= 1)
#pragma unroll
      for (int rg = 0; rg < 4; ++rg) mx[rg] = fmaxf(mx[rg], __shfl_xor(mx[rg], d, 64));
    float al[4], pv0[4], pv1[4], rs[4];
#pragma unroll
    for (int rg = 0; rg < 4; ++rg) {
      float mn = fmaxf(mrun[rg], mx[rg]);
      al[rg] = exp2f(mrun[rg] - mn);
      mrun[rg] = mn;
      pv0[rg] = exp2f(sfr[0][rg] - mn);
      pv1[rg] = exp2f(sfr[1][rg] - mn);
      rs[rg] = pv0[rg] + pv1[rg];
    }
#pragma unroll
    for (int d = 1; d < 16; d <<= 1)
#pragma unroll
      for (int rg = 0; rg < 4; ++rg) rs[rg] += __shfl_xor(rs[rg], d, 64);
    const int prow = wid * 16 + quad * 4;
    u16* pb = &pbuf[buf * 2560];
#pragma unroll
    for (int rg = 0; rg < 4; ++rg) {
      lrun[rg] = lrun[rg] * al[rg] + rs[rg];
      pb[(prow + rg) * 40 + colc] = f2h(pv0[rg]);
      pb[(prow + rg) * 40 + 16 + colc] = f2h(pv1[rg]);
    }
    if (colc == 0) {
#pragma unroll
      for (int rg = 0; rg < 4; ++rg) alpha_s[buf * 64 + prow + rg] = al[rg];
    }
    __syncthreads();  // publishes pbuf/alpha; drains next-kt prefetch
    // PV: this wave's 128 v-dims, all 64 q-rows; V frags straight from global
    half8 vf[8];
    {
      const u16* vp = vrow + t0;
#pragma unroll
      for (int vb = 0; vb < 8; ++vb) vf[vb] = *(const half8*)(vp + (size_t)vb * 32768);
    }
    half8 pf[4];
#pragma unroll
    for (int pa = 0; pa < 4; ++pa) pf[pa] = *(const half8*)&pb[(pa * 16 + colc) * 40 + quad * 8];
    float av[4][4];
#pragma unroll
    for (int pa = 0; pa < 4; ++pa)
#pragma unroll
      for (int rg = 0; rg < 4; ++rg) av[pa][rg] = alpha_s[buf * 64 + pa * 16 + quad * 4 + rg];
#pragma unroll
    for (int pa = 0; pa < 4; ++pa)
#pragma unroll
      for (int vb = 0; vb < 8; ++vb)
#pragma unroll
        for (int rg = 0; rg < 4; ++rg) oacc[pa][vb][rg] *= av[pa][rg];
#pragma unroll
    for (int vb = 0; vb < 8; ++vb)
#pragma unroll
      for (int pa = 0; pa < 4; ++pa) oacc[pa][vb] = mfma16(pf[pa], vf[vb], oacc[pa][vb]);
  }
  {
    const int prow = wid * 16 + quad * 4;
    if (colc == 0) {
#pragma unroll
      for (int rg = 0; rg < 4; ++rg) l_s[prow + rg] = lrun[rg];
    }
  }
  __syncthreads();
  u16* ob = out + ((size_t)b * 2048 + qb * 64) * 4096 + h * 512 + wid * 128;
#pragma unroll
  for (int pa = 0; pa < 4; ++pa) {
    float li[4];
#pragma unroll
    for (int rg = 0; rg < 4; ++rg) li[rg] = 1.0f / l_s[pa * 16 + quad * 4 + rg];
#pragma unroll
    for (int vb = 0; vb < 8; ++vb)
#pragma unroll
      for (int rg = 0; rg < 4; ++rg)
        ob[(size_t)(pa * 16 + quad * 4 + rg) * 4096 + vb * 16 + colc] =
            f2h(oacc[pa][vb][rg] * li[rg]);
  }
}

// ---------------- launcher ----------------
extern "C" void kernel_launch(void* const* d_in, const int* in_sizes, int n_in, void* d_out,
                              int out_size, void* d_ws, size_t ws_size, hipStream_t stream) {
  const float* x = (const float*)d_in[0];
  const float* blade = (const float*)d_in[1];
  const float* w_enter = (const float*)d_in[2];
  const float* w_q = (const float*)d_in[3];
  const float* w_k = (const float*)d_in[4];
  const float* w_v = (const float*)d_in[5];
  const float* w_out = (const float*)d_in[6];
  const float* w_final = (const float*)d_in[7];
  float* out = (float*)d_out;

  char* ws = (char*)d_ws;
  size_t off = 0;
  auto alloc = [&](size_t bytes) {
    void* p = ws + off;
    off = (off + bytes + 255) & ~(size_t)255;
    return p;
  };
  float* wb_enter = (float*)alloc((size_t)32 * 48 * 16 * 4);
  u16* wqkvT = (u16*)alloc((size_t)2816 * 1024 * 2);
  u16* woutT = (u16*)alloc((size_t)512 * 4096 * 2);
  u16* wfinT = (u16*)alloc((size_t)512 * 512 * 2);
  float* hbuf = (float*)alloc((size_t)8192 * 512 * 4);
  u16* hn2 = (u16*)alloc((size_t)8192 * 1024 * 2);
  u16* qkv2 = (u16*)alloc((size_t)8192 * QKV_LD * 2);
  u16* vTb = (u16*)alloc((size_t)4 * 512 * 2048 * 2);
  u16* attno = (u16*)alloc((size_t)8192 * 4096 * 2);
  u16* h2 = (u16*)alloc((size_t)8192 * 512 * 2);

  build_wb_enter<<<96, 256, 0, stream>>>(w_enter, blade, wb_enter);
  build_wqkvT<<<11264, 256, 0, stream>>>(w_q, w_k, w_v, blade, wqkvT);
  build_woutT<<<8192, 256, 0, stream>>>(w_out, blade, woutT);
  build_wfinalT<<<1024, 256, 0, stream>>>(w_final, blade, wfinT);
  enter_norm<<<1024, 256, 0, stream>>>(x, wb_enter, hbuf, hn2);
  gemm_bt<0><<<dim3(22, 64), 256, 0, stream>>>(hn2, wqkvT, 8192, 2816, 1024, qkv2, nullptr,
                                               nullptr, vTb, QKV_LD);
  flash_attn<<<dim3(32, 8, 4), 256, 0, stream>>>(qkv2, vTb, attno);
  gemm_bt<1><<<dim3(4, 64), 256, 0, stream>>>(attno, woutT, 8192, 512, 4096, h2, nullptr, hbuf,
                                              nullptr, 512);
  gemm_bt<2><<<dim3(4, 64), 256, 0, stream>>>(h2, wfinT, 8192, 512, 512, nullptr, out, nullptr,
                                              nullptr, 512);
}